// Round 16
// baseline (66.833 us; speedup 1.0000x reference)
//
#include <hip/hip_runtime.h>
#include <math.h>

#define CC 64
#define RR 4
#define HH 128
#define WW 128
#define BB 8
#define COUT 128
#define XST 72    // xsT row stride in ushorts (144B); XOR-swizzled 8-ch blocks
#define ALS 44    // alp row stride in ushorts (88B; 22 dw -> 2-way max = free)

typedef __attribute__((ext_vector_type(8))) short short8;
typedef __attribute__((ext_vector_type(4))) float f32x4;
typedef __attribute__((ext_vector_type(2))) float f32x2;

__device__ __forceinline__ unsigned short f2bf(float f) {
  unsigned u = __float_as_uint(f);
  u += 0x7fffu + ((u >> 16) & 1u);
  return (unsigned short)(u >> 16);
}
__device__ __forceinline__ float bf2f(unsigned short h) {
  return __uint_as_float(((unsigned)h) << 16);
}
__device__ __forceinline__ float blo(unsigned u) { return __uint_as_float(u << 16); }
__device__ __forceinline__ float bhi(unsigned u) { return __uint_as_float(u & 0xffff0000u); }
// xsT channel-block swizzle: partners 8-apart in sp get distinct banks
__device__ __forceinline__ int swzx(int cb, int sp) { return cb ^ ((sp >> 3) & 7); }
// aggs k-block swizzle: partners 8-apart in row get distinct banks
__device__ __forceinline__ int swza(int cb, int row) { return cb ^ ((row >> 3) & 3); }

// --- K0: kern table + pw -> bf16 + zero-padded gw -> bf16 [16][64]
__global__ __launch_bounds__(256) void k_pre(const float* __restrict__ theta,
                                             const float* __restrict__ rsu,
                                             const float* __restrict__ rss,
                                             const float* __restrict__ pw,
                                             const float* __restrict__ gw,
                                             float* __restrict__ wkern,
                                             unsigned short* __restrict__ pwb,
                                             unsigned short* __restrict__ gwb) {
  int i = blockIdx.x * 256 + threadIdx.x;
  if (i < COUT * RR * CC) pwb[i] = f2bf(pw[i]);
  if (blockIdx.x == 0 && threadIdx.x < RR * 9) {
    int t = threadIdx.x;
    int r = t / 9, s = t % 9;
    float dy = (float)(s / 3 - 1), dx = (float)(s % 3 - 1);
    float ct = cosf(theta[r]), st = sinf(theta[r]);
    float su = log1pf(expf(rsu[r])) + 1e-4f;
    float sv = log1pf(expf(rss[r])) + 1e-4f;
    float pu = ct * dx + st * dy;
    float ps = -st * dx + ct * dy;
    wkern[t] = expf(-(pu * pu) / (su * su) - (ps * ps) / (sv * sv));
  }
  if (blockIdx.x == 1) {
    #pragma unroll
    for (int k = 0; k < 4; ++k) {
      int j = k * 256 + threadIdx.x;     // 0..1023 over [16][64]
      gwb[j] = (j < RR * CC) ? f2bf(gw[j]) : (unsigned short)0;
    }
  }
}

// --- K1: fully fused; 4 rows x 32 cols per 512-thread block; 1024 blocks; 2/CU
__global__ __launch_bounds__(512, 2) void k_fused(const float* __restrict__ x,
                                                  const float* __restrict__ gb,
                                                  const float* __restrict__ wkern,
                                                  const unsigned short* __restrict__ pwb,
                                                  const unsigned short* __restrict__ gwb,
                                                  const float* __restrict__ pb,
                                                  float* __restrict__ out) {
  __shared__ unsigned short xsT[240][XST];   // bf16 x halo [sp=row*40+col][swz ch], rows h0-1..h0+4
  __shared__ unsigned short mus[RR][6][40];  // bf16 mu halo (cols 3..36 valid)
  __shared__ unsigned short alp[128][ALS];   // raw bf16 alpha [px][s*4+r]
  __shared__ float rsum[RR][128];            // per-r raw-alpha sums
  __shared__ __align__(16) unsigned short aggs[32][264];  // bf16 agg per 32-px round

  int tid = threadIdx.x;
  int raw = blockIdx.x;
  int bid = (raw & 7) * 128 + (raw >> 3);    // XCD swizzle (1024 % 8 == 0)
  int b = bid >> 7;
  int rem = bid & 127;
  int h0 = (rem >> 2) << 2;                  // 32 h-tiles of 4 rows
  int w0 = (rem & 3) << 5;                   // 4 w-tiles of 32 cols

  int lane = tid & 63;
  int wv = tid >> 6;                         // 8 waves
  int lr = lane & 15, lq = lane >> 4;
  int oq = wv & 3;                           // o-quadrant (32 rows)
  int ph = wv >> 2;                          // px-half (16 px)
  int o0 = oq << 5;
  int p0 = ph << 4;

  // ---- A-fragments (GEMM, 32 rows/wave over 16-px half) + mu A-frags + bias
  short8 a0r[8], a1r[8];
  {
    const unsigned short* pA = pwb + ((o0 + lr) << 8) + (lq << 3);
    #pragma unroll
    for (int ks = 0; ks < 8; ++ks) {
      a0r[ks] = *(const short8*)(pA + (ks << 5));
      a1r[ks] = *(const short8*)(pA + 4096 + (ks << 5));
    }
  }
  short8 am0 = *(const short8*)(gwb + (lr << 6) + (lq << 3));
  short8 am1 = *(const short8*)(gwb + (lr << 6) + 32 + (lq << 3));
  float4 pbv0 = *(const float4*)&pb[o0 + (lq << 2)];
  float4 pbv1 = *(const float4*)&pb[o0 + 16 + (lq << 2)];
  float gb0 = gb[0], gb1 = gb[1], gb2 = gb[2], gb3 = gb[3];

  // ---- phase A: stage x halo transposed+swizzled; 960 4-channel items
  #pragma unroll
  for (int k = 0; k < 2; ++k) {
    int item = k * 512 + tid;                 // 0..1023
    if (item < 960) {
      int c4 = item % 10;                     // f4 slot in row (0..9)
      int rest = item / 10;                   // 0..95
      int cquad = rest / 6;                   // 0..15
      int row = rest - cquad * 6;             // 0..5
      int c = cquad << 2;
      int gcol = w0 - 4 + (c4 << 2);
      int grow = h0 - 1 + row;
      float4 v0 = make_float4(0.f,0.f,0.f,0.f), v1 = v0, v2 = v0, v3 = v0;
      if ((unsigned)gcol < WW && (unsigned)grow < HH) {
        const float* xp = x + (((size_t)b * CC + c) << 14) + (grow << 7) + gcol;
        v0 = *(const float4*)xp;
        v1 = *(const float4*)(xp + (1 << 14));
        v2 = *(const float4*)(xp + (2 << 14));
        v3 = *(const float4*)(xp + (3 << 14));
      }
      int spb = row * 40 + (c4 << 2);
      int cb = cquad >> 1, sub = (cquad & 1) << 2;
      float4 vv[4] = {v0, v1, v2, v3};
      #pragma unroll
      for (int j = 0; j < 4; ++j) {
        int sp = spb + j;
        float f0 = (&vv[0].x)[j], f1 = (&vv[1].x)[j], f2v = (&vv[2].x)[j], f3 = (&vv[3].x)[j];
        ushort4 uv;
        uv.x = f2bf(f0); uv.y = f2bf(f1); uv.z = f2bf(f2v); uv.w = f2bf(f3);
        *(ushort4*)&xsT[sp][(swzx(cb, sp) << 3) + sub] = uv;
      }
    }
  }
  __syncthreads();

  // ---- phase Mu (MFMA): logits over 6x34=204 positions, 13 16-px tiles, 8 waves
  for (int j = wv; j < 13; j += 8) {
    int p = (j << 4) + lr;
    int pcl = p > 203 ? 203 : p;
    unsigned y = (unsigned)pcl / 34u;
    int cxo = pcl - (int)(y * 34u);
    int pos = (int)y * 40 + 3 + cxo;
    short8 b0 = *(const short8*)&xsT[pos][swzx(lq, pos) << 3];
    short8 b1 = *(const short8*)&xsT[pos][swzx(4 + lq, pos) << 3];
    f32x4 mac = (f32x4){0.f, 0.f, 0.f, 0.f};
    mac = __builtin_amdgcn_mfma_f32_16x16x32_bf16(am0, b0, mac, 0, 0, 0);
    mac = __builtin_amdgcn_mfma_f32_16x16x32_bf16(am1, b1, mac, 0, 0, 0);
    if (lq == 0 && p < 204) {
      int grow = h0 - 1 + (int)y, gcol = w0 - 1 + cxo;
      float lg0 = mac[0] + gb0, lg1 = mac[1] + gb1;
      float lg2 = mac[2] + gb2, lg3 = mac[3] + gb3;
      float m = fmaxf(fmaxf(lg0, lg1), fmaxf(lg2, lg3));
      float e0 = expf(lg0 - m), e1 = expf(lg1 - m);
      float e2 = expf(lg2 - m), e3 = expf(lg3 - m);
      float inv = 1.0f / (e0 + e1 + e2 + e3);
      if (!((unsigned)grow < HH && (unsigned)gcol < WW)) inv = 0.0f;  // zero-pad mu
      mus[0][y][3 + cxo] = f2bf(e0 * inv);
      mus[1][y][3 + cxo] = f2bf(e1 * inv);
      mus[2][y][3 + cxo] = f2bf(e2 * inv);
      mus[3][y][3 + cxo] = f2bf(e3 * inv);
    }
  }
  __syncthreads();

  // ---- phase B: raw alpha (bf16) per (px, r); 512 threads = 128 px x 4 r
  {
    int t = tid & 127, r = tid >> 7;         // r wave-uniform -> wkern scalar loads
    int prow = t >> 5, pcol = t & 31;
    float mc = bf2f(mus[r][prow + 1][pcol + 4]);
    float sum = 0.f;
    #pragma unroll
    for (int s = 0; s < 9; ++s) {
      float av = mc * bf2f(mus[r][prow + s / 3][pcol + 3 + s % 3]) * wkern[r * 9 + s];
      alp[t][(s << 2) + r] = f2bf(av);
      sum += av;
    }
    rsum[r][t] = sum;
  }
  __syncthreads();

  // ---- rounds: 4 x (C: 32-px agg -> D: MFMA + stores)
  for (int rd = 0; rd < 4; ++rd) {
    // phase C: 32 px x 16 c-groups of 4 channels; swizzled b64 per s
    {
      int t = tid & 31, cg = tid >> 5;       // px-in-round, c-group (0..15)
      int px = (rd << 5) + t;
      float inv = 1.0f / fmaxf(rsum[0][px] + rsum[1][px] + rsum[2][px] + rsum[3][px], 1e-8f);

      uint2 ad[9];
      #pragma unroll
      for (int s = 0; s < 9; ++s) ad[s] = *(const uint2*)(&alp[px][s << 2]);

      f32x2 cacc[4][2];
      #pragma unroll
      for (int r = 0; r < 4; ++r) {
        cacc[r][0] = (f32x2){0.f, 0.f};
        cacc[r][1] = (f32x2){0.f, 0.f};
      }

      int cb = cg >> 1, sub = (cg & 1) << 2;
      #pragma unroll
      for (int s = 0; s < 9; ++s) {
        int sp = (rd + s / 3) * 40 + t + 3 + s % 3;
        uint2 ux = *(const uint2*)&xsT[sp][(swzx(cb, sp) << 3) + sub];
        f32x2 xv0 = {blo(ux.x), bhi(ux.x)};
        f32x2 xv1 = {blo(ux.y), bhi(ux.y)};
        unsigned adx = ad[s].x, ady = ad[s].y;
        float af0 = blo(adx), af1 = bhi(adx), af2 = blo(ady), af3 = bhi(ady);
        f32x2 A0 = {af0, af0}, A1 = {af1, af1}, A2 = {af2, af2}, A3 = {af3, af3};
        cacc[0][0] += A0 * xv0; cacc[0][1] += A0 * xv1;
        cacc[1][0] += A1 * xv0; cacc[1][1] += A1 * xv1;
        cacc[2][0] += A2 * xv0; cacc[2][1] += A2 * xv1;
        cacc[3][0] += A3 * xv0; cacc[3][1] += A3 * xv1;
      }
      #pragma unroll
      for (int r = 0; r < 4; ++r) {
        ushort4 wvv;
        wvv.x = f2bf(cacc[r][0][0] * inv); wvv.y = f2bf(cacc[r][0][1] * inv);
        wvv.z = f2bf(cacc[r][1][0] * inv); wvv.w = f2bf(cacc[r][1][1] * inv);
        int kb = (r << 3) + cb;
        *(ushort4*)&aggs[t][(swza(kb, t) << 3) + sub] = wvv;
      }
    }
    __syncthreads();

    // phase D: wave = 32 o-rows x 16-px half; 8 b128 reads, 16 MFMA per round
    {
      f32x4 dacc0 = (f32x4){0.f, 0.f, 0.f, 0.f};
      f32x4 dacc1 = (f32x4){0.f, 0.f, 0.f, 0.f};
      int brow = p0 + lr;
      #pragma unroll
      for (int ks = 0; ks < 8; ++ks) {
        short8 b0 = *(const short8*)&aggs[brow][swza((ks << 2) + lq, brow) << 3];
        dacc0 = __builtin_amdgcn_mfma_f32_16x16x32_bf16(a0r[ks], b0, dacc0, 0, 0, 0);
        dacc1 = __builtin_amdgcn_mfma_f32_16x16x32_bf16(a1r[ks], b0, dacc1, 0, 0, 0);
      }
      int orow = h0 + rd;
      #pragma unroll
      for (int q = 0; q < 4; ++q) {
        int o = o0 + (lq << 2) + q;
        size_t base0 = (((size_t)b * COUT + o) << 14) + (orow << 7) + w0 + p0;
        size_t base1 = (((size_t)b * COUT + o + 16) << 14) + (orow << 7) + w0 + p0;
        out[base0 + lr] = dacc0[q] + pbv0[q];
        out[base1 + lr] = dacc1[q] + pbv1[q];
      }
    }
    if (rd < 3) __syncthreads();   // protect aggs before next round's phase C
  }
}

extern "C" void kernel_launch(void* const* d_in, const int* in_sizes, int n_in,
                              void* d_out, int out_size, void* d_ws, size_t ws_size,
                              hipStream_t stream) {
  const float* x     = (const float*)d_in[0];
  const float* gw    = (const float*)d_in[1];
  const float* gb    = (const float*)d_in[2];
  const float* theta = (const float*)d_in[3];
  const float* rsu   = (const float*)d_in[4];
  const float* rss   = (const float*)d_in[5];
  const float* pw    = (const float*)d_in[6];
  const float* pb    = (const float*)d_in[7];
  float* outp = (float*)d_out;

  float* wkern = (float*)d_ws;                           // 64 floats
  unsigned short* pwb = (unsigned short*)(wkern + 64);   // 32768 bf16
  unsigned short* gwb = pwb + COUT * RR * CC;            // 1024 bf16 [16][64]

  k_pre<<<128, 256, 0, stream>>>(theta, rsu, rss, pw, gw, wkern, pwb, gwb);
  k_fused<<<BB * (HH / 4) * (WW / 32), 512, 0, stream>>>(x, gb, wkern, pwb, gwb, pb, outp);
}

// Round 17
// 49.036 us; speedup vs baseline: 1.3629x; 1.3629x over previous
//
#include <hip/hip_runtime.h>
#include <math.h>

#define CC 64
#define RR 4
#define HH 128
#define WW 128
#define BB 8
#define COUT 128
#define XST 68    // xsT row stride in ushorts (136B = 34 dw == 2 mod 32 -> free b64)
#define ALS 44    // alp row stride in ushorts (88B = 22 dw -> 2-way = free)
#define AGS 268   // aggs row stride in ushorts (536B = 134 dw == 6 mod 32 -> 16-bank spread)

typedef __attribute__((ext_vector_type(8))) short short8;
typedef __attribute__((ext_vector_type(4))) short short4v;
typedef __attribute__((ext_vector_type(4))) float f32x4;
typedef __attribute__((ext_vector_type(2))) float f32x2;

__device__ __forceinline__ unsigned short f2bf(float f) {
  unsigned u = __float_as_uint(f);
  u += 0x7fffu + ((u >> 16) & 1u);
  return (unsigned short)(u >> 16);
}
__device__ __forceinline__ float bf2f(unsigned short h) {
  return __uint_as_float(((unsigned)h) << 16);
}
__device__ __forceinline__ float blo(unsigned u) { return __uint_as_float(u << 16); }
__device__ __forceinline__ float bhi(unsigned u) { return __uint_as_float(u & 0xffff0000u); }

// --- K0: kern table + pw -> bf16 + zero-padded gw -> bf16 [16][64]
__global__ __launch_bounds__(256) void k_pre(const float* __restrict__ theta,
                                             const float* __restrict__ rsu,
                                             const float* __restrict__ rss,
                                             const float* __restrict__ pw,
                                             const float* __restrict__ gw,
                                             float* __restrict__ wkern,
                                             unsigned short* __restrict__ pwb,
                                             unsigned short* __restrict__ gwb) {
  int i = blockIdx.x * 256 + threadIdx.x;
  if (i < COUT * RR * CC) pwb[i] = f2bf(pw[i]);
  if (blockIdx.x == 0 && threadIdx.x < RR * 9) {
    int t = threadIdx.x;
    int r = t / 9, s = t % 9;
    float dy = (float)(s / 3 - 1), dx = (float)(s % 3 - 1);
    float ct = cosf(theta[r]), st = sinf(theta[r]);
    float su = log1pf(expf(rsu[r])) + 1e-4f;
    float sv = log1pf(expf(rss[r])) + 1e-4f;
    float pu = ct * dx + st * dy;
    float ps = -st * dx + ct * dy;
    wkern[t] = expf(-(pu * pu) / (su * su) - (ps * ps) / (sv * sv));
  }
  if (blockIdx.x == 1) {
    #pragma unroll
    for (int k = 0; k < 4; ++k) {
      int j = k * 256 + threadIdx.x;     // 0..1023 over [16][64]
      gwb[j] = (j < RR * CC) ? f2bf(gw[j]) : (unsigned short)0;
    }
  }
}

// --- K1: fully fused; 4 rows x 32 cols per 512-thread block; 1024 blocks; 2/CU
__global__ __launch_bounds__(512, 4) void k_fused(const float* __restrict__ x,
                                                  const float* __restrict__ gb,
                                                  const float* __restrict__ wkern,
                                                  const unsigned short* __restrict__ pwb,
                                                  const unsigned short* __restrict__ gwb,
                                                  const float* __restrict__ pb,
                                                  float* __restrict__ out) {
  __shared__ unsigned short xsT[240][XST];   // bf16 x halo [sp=row*40+col][channel], linear
  __shared__ unsigned short mus[RR][6][40];  // bf16 mu halo (cols 3..36 valid)
  __shared__ unsigned short alp[128][ALS];   // raw bf16 alpha [px][s*4+r]
  __shared__ float rsum[RR][128];            // per-r raw-alpha sums
  __shared__ __align__(16) unsigned short aggs[32][AGS];  // bf16 agg per 32-px round, linear

  int tid = threadIdx.x;
  int raw = blockIdx.x;
  int bid = (raw & 7) * 128 + (raw >> 3);    // XCD swizzle (1024 % 8 == 0)
  int b = bid >> 7;
  int rem = bid & 127;
  int h0 = (rem >> 2) << 2;                  // 32 h-tiles of 4 rows
  int w0 = (rem & 3) << 5;                   // 4 w-tiles of 32 cols

  int lane = tid & 63;
  int wv = tid >> 6;                         // 8 waves
  int lr = lane & 15, lq = lane >> 4;
  int o0 = wv << 4;                          // 16 o-rows per wave

  // ---- A-fragments (GEMM, 16 rows/wave) + mu A-fragments + bias preload
  short8 a0r[8];
  {
    const unsigned short* pA = pwb + ((o0 + lr) << 8) + (lq << 3);
    #pragma unroll
    for (int ks = 0; ks < 8; ++ks) a0r[ks] = *(const short8*)(pA + (ks << 5));
  }
  short8 am0 = *(const short8*)(gwb + (lr << 6) + (lq << 3));
  short8 am1 = *(const short8*)(gwb + (lr << 6) + 32 + (lq << 3));
  float4 pbv = *(const float4*)&pb[o0 + (lq << 2)];
  float gb0 = gb[0], gb1 = gb[1], gb2 = gb[2], gb3 = gb[3];

  // ---- phase A: stage x halo transposed (linear channel index); 960 items
  #pragma unroll
  for (int k = 0; k < 2; ++k) {
    int item = k * 512 + tid;                 // 0..1023
    if (item < 960) {
      int c4 = item % 10;                     // f4 slot in row (0..9)
      int rest = item / 10;                   // 0..95
      int cquad = rest / 6;                   // 0..15
      int row = rest - cquad * 6;             // 0..5
      int c = cquad << 2;
      int gcol = w0 - 4 + (c4 << 2);
      int grow = h0 - 1 + row;
      float4 v0 = make_float4(0.f,0.f,0.f,0.f), v1 = v0, v2 = v0, v3 = v0;
      if ((unsigned)gcol < WW && (unsigned)grow < HH) {
        const float* xp = x + (((size_t)b * CC + c) << 14) + (grow << 7) + gcol;
        v0 = *(const float4*)xp;
        v1 = *(const float4*)(xp + (1 << 14));
        v2 = *(const float4*)(xp + (2 << 14));
        v3 = *(const float4*)(xp + (3 << 14));
      }
      int spb = row * 40 + (c4 << 2);
      float4 vv[4] = {v0, v1, v2, v3};
      #pragma unroll
      for (int j = 0; j < 4; ++j) {
        int sp = spb + j;
        float f0 = (&vv[0].x)[j], f1 = (&vv[1].x)[j], f2v = (&vv[2].x)[j], f3 = (&vv[3].x)[j];
        ushort4 uv;
        uv.x = f2bf(f0); uv.y = f2bf(f1); uv.z = f2bf(f2v); uv.w = f2bf(f3);
        *(ushort4*)&xsT[sp][c] = uv;
      }
    }
  }
  __syncthreads();

  // ---- phase Mu (MFMA): logits over 6x34=204 positions, 13 16-px tiles, 8 waves
  for (int j = wv; j < 13; j += 8) {
    int p = (j << 4) + lr;
    int pcl = p > 203 ? 203 : p;
    unsigned y = (unsigned)pcl / 34u;
    int cxo = pcl - (int)(y * 34u);
    int pos = (int)y * 40 + 3 + cxo;
    short4v b0l = *(const short4v*)&xsT[pos][lq << 3];
    short4v b0h = *(const short4v*)&xsT[pos][(lq << 3) + 4];
    short4v b1l = *(const short4v*)&xsT[pos][32 + (lq << 3)];
    short4v b1h = *(const short4v*)&xsT[pos][32 + (lq << 3) + 4];
    short8 b0 = __builtin_shufflevector(b0l, b0h, 0,1,2,3,4,5,6,7);
    short8 b1 = __builtin_shufflevector(b1l, b1h, 0,1,2,3,4,5,6,7);
    f32x4 mac = (f32x4){0.f, 0.f, 0.f, 0.f};
    mac = __builtin_amdgcn_mfma_f32_16x16x32_bf16(am0, b0, mac, 0, 0, 0);
    mac = __builtin_amdgcn_mfma_f32_16x16x32_bf16(am1, b1, mac, 0, 0, 0);
    if (lq == 0 && p < 204) {
      int grow = h0 - 1 + (int)y, gcol = w0 - 1 + cxo;
      float lg0 = mac[0] + gb0, lg1 = mac[1] + gb1;
      float lg2 = mac[2] + gb2, lg3 = mac[3] + gb3;
      float m = fmaxf(fmaxf(lg0, lg1), fmaxf(lg2, lg3));
      float e0 = expf(lg0 - m), e1 = expf(lg1 - m);
      float e2 = expf(lg2 - m), e3 = expf(lg3 - m);
      float inv = 1.0f / (e0 + e1 + e2 + e3);
      if (!((unsigned)grow < HH && (unsigned)gcol < WW)) inv = 0.0f;  // zero-pad mu
      mus[0][y][3 + cxo] = f2bf(e0 * inv);
      mus[1][y][3 + cxo] = f2bf(e1 * inv);
      mus[2][y][3 + cxo] = f2bf(e2 * inv);
      mus[3][y][3 + cxo] = f2bf(e3 * inv);
    }
  }
  __syncthreads();

  // ---- phase B: raw alpha (bf16) per (px, r); 512 threads = 128 px x 4 r
  {
    int t = tid & 127, r = tid >> 7;         // r wave-uniform -> wkern scalar loads
    int prow = t >> 5, pcol = t & 31;
    float mc = bf2f(mus[r][prow + 1][pcol + 4]);
    float sum = 0.f;
    #pragma unroll
    for (int s = 0; s < 9; ++s) {
      float av = mc * bf2f(mus[r][prow + s / 3][pcol + 3 + s % 3]) * wkern[r * 9 + s];
      alp[t][(s << 2) + r] = f2bf(av);
      sum += av;
    }
    rsum[r][t] = sum;
  }
  __syncthreads();

  // ---- rounds: 4 x (C: 32-px agg -> D: MFMA + full-line stores)
  for (int rd = 0; rd < 4; ++rd) {
    // phase C: 32 px x 16 c-groups of 4 channels; linear b64 reads (free banks)
    {
      int t = tid & 31, cg = tid >> 5;       // px-in-round, c-group (0..15)
      int px = (rd << 5) + t;
      float inv = 1.0f / fmaxf(rsum[0][px] + rsum[1][px] + rsum[2][px] + rsum[3][px], 1e-8f);

      uint2 ad[9];
      #pragma unroll
      for (int s = 0; s < 9; ++s) ad[s] = *(const uint2*)(&alp[px][s << 2]);

      f32x2 cacc[4][2];
      #pragma unroll
      for (int r = 0; r < 4; ++r) {
        cacc[r][0] = (f32x2){0.f, 0.f};
        cacc[r][1] = (f32x2){0.f, 0.f};
      }

      int c0 = cg << 2;
      #pragma unroll
      for (int s = 0; s < 9; ++s) {
        int sp = (rd + s / 3) * 40 + t + 3 + s % 3;
        uint2 ux = *(const uint2*)&xsT[sp][c0];
        f32x2 xv0 = {blo(ux.x), bhi(ux.x)};
        f32x2 xv1 = {blo(ux.y), bhi(ux.y)};
        unsigned adx = ad[s].x, ady = ad[s].y;
        float af0 = blo(adx), af1 = bhi(adx), af2 = blo(ady), af3 = bhi(ady);
        f32x2 A0 = {af0, af0}, A1 = {af1, af1}, A2 = {af2, af2}, A3 = {af3, af3};
        cacc[0][0] += A0 * xv0; cacc[0][1] += A0 * xv1;
        cacc[1][0] += A1 * xv0; cacc[1][1] += A1 * xv1;
        cacc[2][0] += A2 * xv0; cacc[2][1] += A2 * xv1;
        cacc[3][0] += A3 * xv0; cacc[3][1] += A3 * xv1;
      }
      #pragma unroll
      for (int r = 0; r < 4; ++r) {
        ushort4 wvv;
        wvv.x = f2bf(cacc[r][0][0] * inv); wvv.y = f2bf(cacc[r][0][1] * inv);
        wvv.z = f2bf(cacc[r][1][0] * inv); wvv.w = f2bf(cacc[r][1][1] * inv);
        *(ushort4*)&aggs[t][(r << 6) + c0] = wvv;
      }
    }
    __syncthreads();

    // phase D: out[16 o/wave][32 px] slices; b64-pair reads (16-bank spread)
    {
      f32x4 dacc0 = (f32x4){0.f, 0.f, 0.f, 0.f};
      f32x4 dacc1 = (f32x4){0.f, 0.f, 0.f, 0.f};
      #pragma unroll
      for (int ks = 0; ks < 8; ++ks) {
        int off = (ks << 5) + (lq << 3);
        short4v l0 = *(const short4v*)&aggs[lr][off];
        short4v h0 = *(const short4v*)&aggs[lr][off + 4];
        short4v l1 = *(const short4v*)&aggs[16 + lr][off];
        short4v h1 = *(const short4v*)&aggs[16 + lr][off + 4];
        short8 b0 = __builtin_shufflevector(l0, h0, 0,1,2,3,4,5,6,7);
        short8 b1 = __builtin_shufflevector(l1, h1, 0,1,2,3,4,5,6,7);
        dacc0 = __builtin_amdgcn_mfma_f32_16x16x32_bf16(a0r[ks], b0, dacc0, 0, 0, 0);
        dacc1 = __builtin_amdgcn_mfma_f32_16x16x32_bf16(a0r[ks], b1, dacc1, 0, 0, 0);
      }
      int orow = h0 + rd;
      #pragma unroll
      for (int q = 0; q < 4; ++q) {
        int o = o0 + (lq << 2) + q;
        size_t base = (((size_t)b * COUT + o) << 14) + (orow << 7) + w0;
        out[base + lr]      = dacc0[q] + pbv[q];
        out[base + 16 + lr] = dacc1[q] + pbv[q];
      }
    }
    if (rd < 3) __syncthreads();   // protect aggs before next round's phase C
  }
}

extern "C" void kernel_launch(void* const* d_in, const int* in_sizes, int n_in,
                              void* d_out, int out_size, void* d_ws, size_t ws_size,
                              hipStream_t stream) {
  const float* x     = (const float*)d_in[0];
  const float* gw    = (const float*)d_in[1];
  const float* gb    = (const float*)d_in[2];
  const float* theta = (const float*)d_in[3];
  const float* rsu   = (const float*)d_in[4];
  const float* rss   = (const float*)d_in[5];
  const float* pw    = (const float*)d_in[6];
  const float* pb    = (const float*)d_in[7];
  float* outp = (float*)d_out;

  float* wkern = (float*)d_ws;                           // 64 floats
  unsigned short* pwb = (unsigned short*)(wkern + 64);   // 32768 bf16
  unsigned short* gwb = pwb + COUT * RR * CC;            // 1024 bf16 [16][64]

  k_pre<<<128, 256, 0, stream>>>(theta, rsu, rss, pw, gw, wkern, pwb, gwb);
  k_fused<<<BB * (HH / 4) * (WW / 32), 512, 0, stream>>>(x, gb, wkern, pwb, gwb, pb, outp);
}